// Round 14
// baseline (152.808 us; speedup 1.0000x reference)
//
#include <hip/hip_runtime.h>

// CQT on gfx950 — v19: 2-dispatch pipeline. wfused2 = aprep merged via LDS-staged
// A' (coalesced reads, unlike v12's failed per-lane fusion) + v14 cqt verbatim.
//   Wr[b,n] = sum_k kr[b,k]*wcos[k,n] - ki[b,k]*wsin[k,n]
//   Wi[b,n] = sum_k kr[b,k]*wsin[k,n] + ki[b,k]*wcos[k,n]
//   cqt[b,f] = sqrt((sum_n x[512f+n]*W[2b,n])^2 + (sum_n x[512f+n]*W[2b+1,n])^2)
// Ledger: v14 117.7 best; aprep+wfused work ~4-5us but pipeline carries ~5-7us
// per dependent-dispatch boundary. v19 removes one boundary + the Apf HBM
// round-trip. v18's 5-bit swizzle was null -> cqt reverted to v14's exact form.
// K1 wfused2: grid 192 x 512 (mt = bid>>5, ntpair = bid&31). LDS 156.7 KB:
//   As[129][512] bf16 (A' tile, frag order) + red[2][3][4][64] float4.
//   Phase 1: 8256 octets: thread reads 8 CONSECUTIVE f32 of one A'-row
//            (coalesced; aprep's exact guards -> bit-identical bf16), writes
//            one 16B frag-order LDS cell As[k16][(h*32+row)*8].
//   Phase 2: 8 waves = 2 nt x 4 K-split (33/33/33/30). B-frag = contiguous
//            conflict-free ds_read_b128 from As; trig A-operand in-register
//            (phase exact int mod 2048, v_cos/v_sin revolutions); mfma 32x32x16.
//   Phase 3: 4-way LDS reduce per nt; s==0 wave packs bf16 -> Wpf frag order.
// K2 cqt: (= v14) grid 256 x 768, 12 waves = 2fg x 6mg, 64-frame blocks,
//   span-linear LDS XOR swizzle byte^(((byte>>10)&7)<<4), one ds_read_b128
//   B-frag, A from Wpf frag order with 8-deep double-buffered reg prefetch.

#define HOPS 512
#define NBINS 84
#define FREQB 1025
#define NFRAMES 16381
#define TSAMP 8388608
#define SPAN 34304            // 63*512 + 2048  (shorts in span; 68,608 B LDS)

typedef short bf16x8 __attribute__((ext_vector_type(8)));
typedef float f32x16 __attribute__((ext_vector_type(16)));

union B8 { struct { ushort4 lo, hi; } p; bf16x8 v; uint4 u; };

__device__ __forceinline__ unsigned short f32_to_bf16(float f) {
    union { float f; unsigned u; } v; v.f = f;
    return (unsigned short)((v.u + 0x7FFFu + ((v.u >> 16) & 1u)) >> 16);
}
__device__ __forceinline__ unsigned pk_bf16(float lo, float hi) {
    return (unsigned)f32_to_bf16(lo) | ((unsigned)f32_to_bf16(hi) << 16);
}
__device__ __forceinline__ bf16x8 pack8(const float* s) {
    B8 r;
    r.u.x = pk_bf16(s[0], s[1]); r.u.y = pk_bf16(s[2], s[3]);
    r.u.z = pk_bf16(s[4], s[5]); r.u.w = pk_bf16(s[6], s[7]);
    return r.v;
}

// cos/sin with input in revolutions (maps to v_cos_f32 / v_sin_f32)
__device__ __forceinline__ float cos_rev(float r) { return __builtin_amdgcn_cosf(r); }
__device__ __forceinline__ float sin_rev(float r) { return __builtin_amdgcn_sinf(r); }

// ---------------- K1: wfused2 — LDS-staged A' + trig GEMM -> Wpf ----------------
__global__ __launch_bounds__(512) void wfused2_kernel(
    const float* __restrict__ kr, const float* __restrict__ ki,
    unsigned short* __restrict__ Wpf)
{
    __shared__ __align__(16) unsigned short As[129 * 512];   // 132,096 B frag-order
    __shared__ float4 red[2][3][4][64];                      //  24,576 B

    const int bid = blockIdx.x;
    const int mt = bid >> 5, ntg = bid & 31;
    const int t = threadIdx.x;

    // ---- Phase 1: stage A'[mt] rows 0..31, k 0..2063 into As (frag order) ----
    // item = row*258 + o (o = octet of 8 consecutive k). Consecutive threads ->
    // consecutive 32B global reads (coalesced). LDS write: As[k16][(h*32+row)*8].
    for (int item = t; item < 32 * 258; item += 512) {
        const int row = item / 258, o = item % 258;
        const int arow = mt * 32 + row;
        const int b = arow >> 1, im = arow & 1;
        const bool bok = b < NBINS;
        const float* cosp = (im ? ki : kr) + (size_t)(bok ? b : 0) * FREQB;
        const float* sinp = (im ? kr : ki) + (size_t)(bok ? b : 0) * FREQB;
        const float ssign = im ? 1.f : -1.f;
        const int k0 = o * 8;
        unsigned short ov[8];
        #pragma unroll
        for (int j = 0; j < 8; ++j) {
            int k = k0 + j;
            float v = 0.f;
            if (bok) {
                if (k <= 1024)       v = cosp[k];
                else if (k <= 2049)  v = ssign * sinp[k - 1025];
            }
            ov[j] = f32_to_bf16(v);
        }
        uint4 pk;
        pk.x = (unsigned)ov[0] | ((unsigned)ov[1] << 16);
        pk.y = (unsigned)ov[2] | ((unsigned)ov[3] << 16);
        pk.z = (unsigned)ov[4] | ((unsigned)ov[5] << 16);
        pk.w = (unsigned)ov[6] | ((unsigned)ov[7] << 16);
        const int k16 = o >> 1, h = o & 1;
        *(uint4*)(As + (size_t)k16 * 512 + (size_t)(h * 32 + row) * 8) = pk;
    }
    __syncthreads();

    // ---- Phase 2: trig GEMM. 8 waves = 2 nt x 4 K-split ----
    const int w = t >> 6, l = t & 63;
    const int nl = w >> 2, s = w & 3;
    const int c32 = l & 31, h = l >> 5;
    const int nt = ntg * 2 + nl;
    const int n = nt * 32 + c32;

    f32x16 acc;
    #pragma unroll
    for (int i = 0; i < 16; ++i) acc[i] = 0.f;

    const int k0 = s * 33;
    const int kcnt = (s < 3) ? 33 : 30;   // covers k16 = 0..128

    for (int i = 0; i < kcnt; ++i) {
        const int k16 = k0 + i;
        B8 bf; bf.u = *(const uint4*)(As + (size_t)k16 * 512 + (size_t)l * 8);
        float tv[8];
        const int kb = k16 * 16 + h * 8;
        if (k16 <= 63) {                       // pure cos rows
            #pragma unroll
            for (int j = 0; j < 8; ++j) {
                int p = __mul24(kb + j, n) & 2047;
                tv[j] = cos_rev((float)p * (1.f / 2048.f));
            }
        } else if (k16 >= 65 && k16 <= 127) {  // pure sin rows (m = k-1025)
            #pragma unroll
            for (int j = 0; j < 8; ++j) {
                int p = __mul24(kb + j - 1025, n) & 2047;
                tv[j] = sin_rev((float)p * (1.f / 2048.f));
            }
        } else {                               // mixed k16==64 or 128 (+ zero tail)
            #pragma unroll
            for (int j = 0; j < 8; ++j) {
                int k = kb + j;
                float v = 0.f;
                if (k <= 1024) {
                    int p = __mul24(k, n) & 2047;
                    v = cos_rev((float)p * (1.f / 2048.f));
                } else if (k <= 2049) {
                    int p = __mul24(k - 1025, n) & 2047;
                    v = sin_rev((float)p * (1.f / 2048.f));
                }
                tv[j] = v;
            }
        }
        acc = __builtin_amdgcn_mfma_f32_32x32x16_bf16(pack8(tv), bf.v, acc, 0, 0, 0);
    }

    // ---- Phase 3: 4-way reduce per nt, pack -> Wpf ----
    if (s > 0) {
        #pragma unroll
        for (int q = 0; q < 4; ++q)
            red[nl][s - 1][q][l] = make_float4(acc[4*q+0], acc[4*q+1],
                                               acc[4*q+2], acc[4*q+3]);
    }
    __syncthreads();
    if (s == 0) {
        #pragma unroll
        for (int e = 0; e < 3; ++e) {
            #pragma unroll
            for (int q = 0; q < 4; ++q) {
                float4 v = red[nl][e][q][l];
                acc[4*q+0] += v.x; acc[4*q+1] += v.y;
                acc[4*q+2] += v.z; acc[4*q+3] += v.w;
            }
        }
        #pragma unroll
        for (int g = 0; g < 4; ++g) {
            uint2 qo;
            qo.x = pk_bf16(acc[4*g+0], acc[4*g+1]);
            qo.y = pk_bf16(acc[4*g+2], acc[4*g+3]);
            size_t off = (size_t)(mt * 128 + nt * 2 + (g >> 1)) * 512
                       + (size_t)(c32 + 32 * (g & 1)) * 8 + 4 * h;
            *(uint2*)(Wpf + off) = qo;   // 8B, coalesced 512B per g
        }
    }
}

// ---------------- K2: main GEMM (v14 verbatim) ----------------
// grid 256 x 768. Block: frames f0..f0+63, all 192 rows. 12 waves: mg=w>>1,
// fg=w&1. mfma 32x32x16, acc 16. A from Wpf (frag order, coalesced), 8-deep
// double-buffered register prefetch. B = one ds_read_b128 per k16 from
// XOR-swizzled span-linear LDS: bsw = byte ^ (((byte>>10)&7)<<4).
__global__ __launch_bounds__(768) void cqt_kernel(
    const float* __restrict__ x, const unsigned short* __restrict__ Wpf,
    float* __restrict__ out)
{
    __shared__ __align__(16) unsigned short xl[SPAN];   // 68,608 B

    const int t = threadIdx.x;
    const int f0 = blockIdx.x * 64;
    const long S0 = (long)f0 * HOPS;
    const int valid = (int)((TSAMP - S0) < (long)SPAN ? (TSAMP - S0) : (long)SPAN);

    // stage x-span once: 8576 float4 over 768 threads, swizzled 8B stores
    #pragma unroll
    for (int i = 0; i < 12; ++i) {
        int idx4 = t + i * 768;
        if (idx4 < 8576) {
            int s = idx4 * 4;
            float4 v = make_float4(0.f, 0.f, 0.f, 0.f);
            if (s + 4 <= valid) v = *(const float4*)(x + S0 + s);
            ushort4 o;
            o.x = f32_to_bf16(v.x); o.y = f32_to_bf16(v.y);
            o.z = f32_to_bf16(v.z); o.w = f32_to_bf16(v.w);
            int byte = idx4 * 8;
            int bsw = byte ^ (((byte >> 10) & 7) << 4);
            *(ushort4*)((char*)xl + bsw) = o;
        }
    }
    __syncthreads();   // the only barrier

    const int w = t >> 6, l = t & 63;
    const int mg = w >> 1, fg = w & 1;
    const int c32 = l & 31, h = l >> 5;

    const unsigned short* apf = Wpf + (size_t)mg * (128 * 512) + (size_t)l * 8;  // +k16*512
    const int byteBase = (fg * 32 + c32) * 1024 + h * 16;

    f32x16 acc;
    #pragma unroll
    for (int i = 0; i < 16; ++i) acc[i] = 0.f;

    auto ldsB = [&](int k16) -> bf16x8 {
        int byte = byteBase + k16 * 32;
        int bsw = byte ^ (((byte >> 10) & 7) << 4);
        B8 r;
        r.u = *(const uint4*)((const char*)xl + bsw);
        return r.v;
    };

    uint4 Abuf[2][8];
    #pragma unroll
    for (int j = 0; j < 8; ++j)
        Abuf[0][j] = *(const uint4*)(apf + (size_t)j * 512);

    #pragma unroll
    for (int c = 0; c < 16; ++c) {
        const int cur = c & 1, nxt = cur ^ 1;
        if (c < 15) {
            #pragma unroll
            for (int j = 0; j < 8; ++j)
                Abuf[nxt][j] = *(const uint4*)(apf + (size_t)((c + 1) * 8 + j) * 512);
        }
        #pragma unroll
        for (int j = 0; j < 8; ++j) {
            B8 af; af.u = Abuf[cur][j];
            acc = __builtin_amdgcn_mfma_f32_32x32x16_bf16(af.v, ldsB(c * 8 + j), acc, 0, 0, 0);
        }
    }

    // epilogue: C/D col=c32 (f), row=(r&3)+8*(r>>2)+4*h; (Wr,Wi) pairs -> magnitude
    const int f = f0 + fg * 32 + c32;
    if (f < NFRAMES) {
        #pragma unroll
        for (int rp = 0; rp < 4; ++rp) {
            int base = mg * 32 + 8 * rp + 4 * h;   // even
            int b0 = base >> 1;
            float r0 = acc[4 * rp + 0], i0 = acc[4 * rp + 1];
            float r1 = acc[4 * rp + 2], i1 = acc[4 * rp + 3];
            if (b0 < NBINS)
                out[(size_t)b0 * NFRAMES + f] = sqrtf(r0 * r0 + i0 * i0);
            if (b0 + 1 < NBINS)
                out[(size_t)(b0 + 1) * NFRAMES + f] = sqrtf(r1 * r1 + i1 * i1);
        }
    }
}

extern "C" void kernel_launch(void* const* d_in, const int* in_sizes, int n_in,
                              void* d_out, int out_size, void* d_ws, size_t ws_size,
                              hipStream_t stream) {
    const float* x    = (const float*)d_in[0];
    // d_in[1] (wcos) and d_in[2] (wsin) unused — trig generated on-device.
    const float* kr   = (const float*)d_in[3];
    const float* ki   = (const float*)d_in[4];
    float* out = (float*)d_out;

    unsigned short* Wpf = (unsigned short*)d_ws;   // 786,432 B

    wfused2_kernel<<<dim3(192), dim3(512), 0, stream>>>(kr, ki, Wpf);
    cqt_kernel<<<dim3(256), dim3(768), 0, stream>>>(x, Wpf, out);
}

// Round 15
// 120.001 us; speedup vs baseline: 1.2734x; 1.2734x over previous
//
#include <hip/hip_runtime.h>

// CQT on gfx950 — v20 == v14 (best measured: 117.7us), locked in after v15-v19
// exploration all regressed. 3-dispatch pipeline:
//   Wr[b,n] = sum_k kr[b,k]*wcos[k,n] - ki[b,k]*wsin[k,n]
//   Wi[b,n] = sum_k kr[b,k]*wsin[k,n] + ki[b,k]*wcos[k,n]
//   cqt[b,f] = sqrt((sum_n x[512f+n]*W[2b,n])^2 + (sum_n x[512f+n]*W[2b+1,n])^2)
// Ledger (measured): cqt-variant swizzles null (v8/v13/v18 118-121); occupancy
// and A-reuse restructures regress (v10/v11); fusing kr/ki ingestion into any
// low-parallelism kernel costs ~+35-42us (v12/v19 — conditional scalar loads,
// latency-bound); monolith regress (v15/v16/v17: 205/80/102us kernel). aprep
// needs massive block parallelism (960x64) to hide cold kr/ki gather latency.
// K1 aprep:   coalesced 8-consecutive-float reads per lane, frag-order scattered
//             16B stores -> Apf[192][2208] bf16 (MFMA-frag order [mt][k16][lane]x8).
// K2 wfused:  W = A' x Trig -> Wpf bf16 frag order; A-frags coalesced from Apf;
//             trig in-register (phase exact int mod 2048, v_cos/v_sin revs).
//             384 tiles x 8 waves, K split 17+7x16, LDS reduce.
// K3 cqt:     grid 256 x 768, 12 waves = 2fg x 6mg, 64-frame blocks.
//             Span-linear LDS, XOR swizzle byte^(((byte>>10)&7)<<4), B-frag =
//             one ds_read_b128; A from Wpf with 8-deep double-buffered prefetch.

#define HOPS 512
#define NBINS 84
#define FREQB 1025
#define NFRAMES 16381
#define TSAMP 8388608
#define SPAN 34304            // 63*512 + 2048  (shorts in span; 68,608 B LDS)
#define KP16 138              // k16 slots in A' K dim (2208)

typedef short bf16x8 __attribute__((ext_vector_type(8)));
typedef float f32x16 __attribute__((ext_vector_type(16)));

union B8 { struct { ushort4 lo, hi; } p; bf16x8 v; uint4 u; };

__device__ __forceinline__ unsigned short f32_to_bf16(float f) {
    union { float f; unsigned u; } v; v.f = f;
    return (unsigned short)((v.u + 0x7FFFu + ((v.u >> 16) & 1u)) >> 16);
}
__device__ __forceinline__ unsigned pk_bf16(float lo, float hi) {
    return (unsigned)f32_to_bf16(lo) | ((unsigned)f32_to_bf16(hi) << 16);
}
__device__ __forceinline__ bf16x8 pack8(const float* s) {
    B8 r;
    r.u.x = pk_bf16(s[0], s[1]); r.u.y = pk_bf16(s[2], s[3]);
    r.u.z = pk_bf16(s[4], s[5]); r.u.w = pk_bf16(s[6], s[7]);
    return r.v;
}

// cos/sin with input in revolutions (maps to v_cos_f32 / v_sin_f32)
__device__ __forceinline__ float cos_rev(float r) { return __builtin_amdgcn_cosf(r); }
__device__ __forceinline__ float sin_rev(float r) { return __builtin_amdgcn_sinf(r); }

// ---------------- K1: A' prep, coalesced reads, scattered frag-order stores ----
// grid 960 x 64: bid = row*5 + c. Lane l: q = c*64 + l (uint4 index, q<276),
// k-run = q*8 .. q*8+7 (CONSECUTIVE -> coalesced reads).
// Dest (frag order): mt=row>>5, c32=row&31, k16=q>>1, h=q&1.
__global__ __launch_bounds__(64) void aprep_kernel(
    const float* __restrict__ kr, const float* __restrict__ ki,
    unsigned short* __restrict__ Apf)
{
    const int bid = blockIdx.x;
    const int row = bid / 5, c = bid % 5;
    const int l = threadIdx.x;
    const int q = c * 64 + l;
    if (q >= 276) return;

    const int b = row >> 1, im = row & 1;
    const bool bok = b < NBINS;
    const float* cosp = (im ? ki : kr) + (size_t)(bok ? b : 0) * FREQB;
    const float* sinp = (im ? kr : ki) + (size_t)(bok ? b : 0) * FREQB;
    const float ssign = im ? 1.f : -1.f;

    const int k0 = q * 8;
    unsigned short o[8];
    #pragma unroll
    for (int j = 0; j < 8; ++j) {
        int k = k0 + j;
        float v = 0.f;
        if (bok) {
            if (k <= 1024)       v = cosp[k];
            else if (k <= 2049)  v = ssign * sinp[k - 1025];
        }
        o[j] = f32_to_bf16(v);
    }
    uint4 pk;
    pk.x = (unsigned)o[0] | ((unsigned)o[1] << 16);
    pk.y = (unsigned)o[2] | ((unsigned)o[3] << 16);
    pk.z = (unsigned)o[4] | ((unsigned)o[5] << 16);
    pk.w = (unsigned)o[6] | ((unsigned)o[7] << 16);

    const int mt = row >> 5, c32 = row & 31;
    const int k16 = q >> 1, h = q & 1;
    *(uint4*)(Apf + (size_t)(mt * KP16 + k16) * 512 + (size_t)(h * 32 + c32) * 8) = pk;
}

// ---------------- K2: fused W GEMM -> Wpf (frag order, bf16) ----------------
// grid 384 x 512: mt = bid>>6 (0..5), nt = bid&63. 8 waves split K (129 k16:
// w0 17, w1-7 16). Swapped mfma: D = Trig^T(32n x 16k) * A'^T(16k x 32row).
// D layout: lane col c32 = W-row-in-tile; D-row (=n_tile) = (r&3)+8*(r>>2)+4h.
// Frag store per quad g: Wpf[(mt*128 + nt*2 + (g>>1))*512 + (c32+32*(g&1))*8 + 4h + (r&3)]
__global__ __launch_bounds__(512) void wfused_kernel(
    const unsigned short* __restrict__ Apf, unsigned short* __restrict__ Wpf)
{
    __shared__ float4 red[7][4][64];   // 28 KB cross-wave reduce

    const int bid = blockIdx.x;
    const int mt = bid >> 6, nt = bid & 63;
    const int t = threadIdx.x;
    const int w = t >> 6, l = t & 63;
    const int c32 = l & 31, h = l >> 5;
    const int n = nt * 32 + c32;

    f32x16 acc;
    #pragma unroll
    for (int i = 0; i < 16; ++i) acc[i] = 0.f;

    const int k0 = (w == 0) ? 0 : 16 * w + 1;
    const int kcnt = (w == 0) ? 17 : 16;   // covers k16 = 0..128
    const unsigned short* ap = Apf + (size_t)(mt * KP16 + k0) * 512 + (size_t)l * 8;

    for (int i = 0; i < kcnt; ++i) {
        const int k16 = k0 + i;
        B8 bf; bf.u = *(const uint4*)(ap + (size_t)i * 512);
        float tv[8];
        const int kb = k16 * 16 + h * 8;
        if (k16 <= 63) {                       // pure cos rows
            #pragma unroll
            for (int j = 0; j < 8; ++j) {
                int p = __mul24(kb + j, n) & 2047;
                tv[j] = cos_rev((float)p * (1.f / 2048.f));
            }
        } else if (k16 >= 65 && k16 <= 127) {  // pure sin rows (m = k-1025)
            #pragma unroll
            for (int j = 0; j < 8; ++j) {
                int p = __mul24(kb + j - 1025, n) & 2047;
                tv[j] = sin_rev((float)p * (1.f / 2048.f));
            }
        } else {                               // mixed k16==64 or 128 (+ zero tail)
            #pragma unroll
            for (int j = 0; j < 8; ++j) {
                int k = kb + j;
                float v = 0.f;
                if (k <= 1024) {
                    int p = __mul24(k, n) & 2047;
                    v = cos_rev((float)p * (1.f / 2048.f));
                } else if (k <= 2049) {
                    int p = __mul24(k - 1025, n) & 2047;
                    v = sin_rev((float)p * (1.f / 2048.f));
                }
                tv[j] = v;
            }
        }
        acc = __builtin_amdgcn_mfma_f32_32x32x16_bf16(pack8(tv), bf.v, acc, 0, 0, 0);
    }

    if (w > 0) {
        #pragma unroll
        for (int q = 0; q < 4; ++q)
            red[w - 1][q][l] = make_float4(acc[4*q+0], acc[4*q+1], acc[4*q+2], acc[4*q+3]);
    }
    __syncthreads();
    if (w == 0) {
        #pragma unroll
        for (int s = 0; s < 7; ++s) {
            #pragma unroll
            for (int q = 0; q < 4; ++q) {
                float4 v = red[s][q][l];
                acc[4*q+0] += v.x; acc[4*q+1] += v.y;
                acc[4*q+2] += v.z; acc[4*q+3] += v.w;
            }
        }
        #pragma unroll
        for (int g = 0; g < 4; ++g) {
            uint2 qo;
            qo.x = pk_bf16(acc[4*g+0], acc[4*g+1]);
            qo.y = pk_bf16(acc[4*g+2], acc[4*g+3]);
            size_t off = (size_t)(mt * 128 + nt * 2 + (g >> 1)) * 512
                       + (size_t)(c32 + 32 * (g & 1)) * 8 + 4 * h;
            *(uint2*)(Wpf + off) = qo;   // 8B, coalesced 512B per g
        }
    }
}

// ---------------- K3: main GEMM, swizzled-b128 LDS ----------------
// grid 256 x 768. Block: frames f0..f0+63, all 192 rows. 12 waves: mg=w>>1,
// fg=w&1. mfma 32x32x16, acc 16. A from Wpf (frag order, coalesced), 8-deep
// double-buffered register prefetch. B = one ds_read_b128 per k16 from
// XOR-swizzled span-linear LDS: bsw = byte ^ (((byte>>10)&7)<<4).
__global__ __launch_bounds__(768) void cqt_kernel(
    const float* __restrict__ x, const unsigned short* __restrict__ Wpf,
    float* __restrict__ out)
{
    __shared__ __align__(16) unsigned short xl[SPAN];   // 68,608 B

    const int t = threadIdx.x;
    const int f0 = blockIdx.x * 64;
    const long S0 = (long)f0 * HOPS;
    const int valid = (int)((TSAMP - S0) < (long)SPAN ? (TSAMP - S0) : (long)SPAN);

    // stage x-span once: 8576 float4 over 768 threads, swizzled 8B stores
    #pragma unroll
    for (int i = 0; i < 12; ++i) {
        int idx4 = t + i * 768;
        if (idx4 < 8576) {
            int s = idx4 * 4;
            float4 v = make_float4(0.f, 0.f, 0.f, 0.f);
            if (s + 4 <= valid) v = *(const float4*)(x + S0 + s);
            ushort4 o;
            o.x = f32_to_bf16(v.x); o.y = f32_to_bf16(v.y);
            o.z = f32_to_bf16(v.z); o.w = f32_to_bf16(v.w);
            int byte = idx4 * 8;
            int bsw = byte ^ (((byte >> 10) & 7) << 4);
            *(ushort4*)((char*)xl + bsw) = o;
        }
    }
    __syncthreads();   // the only barrier

    const int w = t >> 6, l = t & 63;
    const int mg = w >> 1, fg = w & 1;
    const int c32 = l & 31, h = l >> 5;

    const unsigned short* apf = Wpf + (size_t)mg * (128 * 512) + (size_t)l * 8;  // +k16*512
    const int byteBase = (fg * 32 + c32) * 1024 + h * 16;

    f32x16 acc;
    #pragma unroll
    for (int i = 0; i < 16; ++i) acc[i] = 0.f;

    auto ldsB = [&](int k16) -> bf16x8 {
        int byte = byteBase + k16 * 32;
        int bsw = byte ^ (((byte >> 10) & 7) << 4);
        B8 r;
        r.u = *(const uint4*)((const char*)xl + bsw);
        return r.v;
    };

    uint4 Abuf[2][8];
    #pragma unroll
    for (int j = 0; j < 8; ++j)
        Abuf[0][j] = *(const uint4*)(apf + (size_t)j * 512);

    #pragma unroll
    for (int c = 0; c < 16; ++c) {
        const int cur = c & 1, nxt = cur ^ 1;
        if (c < 15) {
            #pragma unroll
            for (int j = 0; j < 8; ++j)
                Abuf[nxt][j] = *(const uint4*)(apf + (size_t)((c + 1) * 8 + j) * 512);
        }
        #pragma unroll
        for (int j = 0; j < 8; ++j) {
            B8 af; af.u = Abuf[cur][j];
            acc = __builtin_amdgcn_mfma_f32_32x32x16_bf16(af.v, ldsB(c * 8 + j), acc, 0, 0, 0);
        }
    }

    // epilogue: C/D col=c32 (f), row=(r&3)+8*(r>>2)+4*h; (Wr,Wi) pairs -> magnitude
    const int f = f0 + fg * 32 + c32;
    if (f < NFRAMES) {
        #pragma unroll
        for (int rp = 0; rp < 4; ++rp) {
            int base = mg * 32 + 8 * rp + 4 * h;   // even
            int b0 = base >> 1;
            float r0 = acc[4 * rp + 0], i0 = acc[4 * rp + 1];
            float r1 = acc[4 * rp + 2], i1 = acc[4 * rp + 3];
            if (b0 < NBINS)
                out[(size_t)b0 * NFRAMES + f] = sqrtf(r0 * r0 + i0 * i0);
            if (b0 + 1 < NBINS)
                out[(size_t)(b0 + 1) * NFRAMES + f] = sqrtf(r1 * r1 + i1 * i1);
        }
    }
}

extern "C" void kernel_launch(void* const* d_in, const int* in_sizes, int n_in,
                              void* d_out, int out_size, void* d_ws, size_t ws_size,
                              hipStream_t stream) {
    const float* x    = (const float*)d_in[0];
    // d_in[1] (wcos) and d_in[2] (wsin) unused — trig generated on-device.
    const float* kr   = (const float*)d_in[3];
    const float* ki   = (const float*)d_in[4];
    float* out = (float*)d_out;

    unsigned short* Wpf = (unsigned short*)d_ws;                    // 786,432 B
    unsigned short* Apf = (unsigned short*)((char*)d_ws + 786432);  // 847,872 B

    aprep_kernel<<<dim3(960), dim3(64), 0, stream>>>(kr, ki, Apf);
    wfused_kernel<<<dim3(384), dim3(512), 0, stream>>>(Apf, Wpf);
    cqt_kernel<<<dim3(256), dim3(768), 0, stream>>>(x, Wpf, out);
}